// Round 8
// baseline (433.757 us; speedup 1.0000x reference)
//
#include <hip/hip_runtime.h>
#include <cstdint>
#include <cfloat>

#define NN 100000
#define NE 1600000
#define NBKT 391          // buckets of 256 dst nodes: (NN+255)/256
#define CHUNK 4096
#define NBLK1 391         // ceil(NE/CHUNK)
#define CAP3 5120         // max edges per bucket (mean 4096, sigma ~64 -> 16 sigma)

typedef short s16x8 __attribute__((ext_vector_type(8)));
typedef float f32x4 __attribute__((ext_vector_type(4)));

#define SCL06 0.8656170245333781f   // 0.6 * log2(e)
#define SCL04 0.5770780163555854f   // 0.4 * log2(e)

__device__ __forceinline__ unsigned short f2bf(float v) {
    unsigned u = __float_as_uint(v);
    unsigned r = u + 0x7fffu + ((u >> 16) & 1u);
    return (unsigned short)(r >> 16);
}

// wave-0 exclusive scan of cnt[0..nelem) -> lst; caller guards threadIdx.x < 64
__device__ __forceinline__ void excl_scan_lds(const int* cnt, int* lst, int nelem, int per_lane) {
    int lane = threadIdx.x & 63;
    int base = lane * per_lane;
    int run = 0;
    int loc[16];
    for (int j = 0; j < per_lane; ++j) {
        int idx = base + j;
        loc[j] = run;
        if (idx < nelem) run += cnt[idx];
    }
    int tot = run;
    for (int off = 1; off < 64; off <<= 1) {
        int t = __shfl_up(tot, off);
        if (lane >= off) tot += t;
    }
    int pre = tot - run;
    for (int j = 0; j < per_lane; ++j) {
        int idx = base + j;
        if (idx < nelem) lst[idx] = pre + loc[j];
    }
}

// ---------------- CSR build: atomic-free bucket sort ----------------
__global__ __launch_bounds__(512) void k_bcount(const int* __restrict__ dst, int* __restrict__ counts) {
    __shared__ int h[NBKT];
    int tid = threadIdx.x, blk = blockIdx.x;
    for (int i = tid; i < NBKT; i += 512) h[i] = 0;
    __syncthreads();
    int e0 = blk * CHUNK, ee = min(e0 + CHUNK, NE);
    for (int i = e0 + tid; i < ee; i += 512) atomicAdd(&h[dst[i] >> 8], 1);
    __syncthreads();
    for (int i = tid; i < NBKT; i += 512) counts[i * NBLK1 + blk] = h[i];
}

// per-bucket segmented exclusive scan over chunks (in place) + bucket totals
__global__ __launch_bounds__(512) void k_bscan(int* __restrict__ counts, int* __restrict__ T) {
    __shared__ int row[NBLK1];
    __shared__ int lst[NBLK1];
    int b = blockIdx.x, tid = threadIdx.x;
    for (int i = tid; i < NBLK1; i += 512) row[i] = counts[(size_t)b * NBLK1 + i];
    __syncthreads();
    if (tid < 64) excl_scan_lds(row, lst, NBLK1, 7);
    __syncthreads();
    for (int i = tid; i < NBLK1; i += 512) counts[(size_t)b * NBLK1 + i] = lst[i];
    if (tid == 0) T[b] = lst[NBLK1 - 1] + row[NBLK1 - 1];
}

// re-read chunk, rank edges in LDS, reorder bucket-major, stream out packed words
// (scans bucket totals T in-LDS itself; no serial global scan kernel)
__global__ __launch_bounds__(512) void k_bscatter(const int* __restrict__ dst, const int* __restrict__ src,
                                                  const int* __restrict__ O, const int* __restrict__ T,
                                                  int* __restrict__ bpacked) {
    __shared__ int cnt[NBKT];
    __shared__ int lst[NBKT];
    __shared__ int cur[NBKT];
    __shared__ int gbase[NBKT];
    __shared__ int tg[NBKT];
    __shared__ int bg[NBKT];
    __shared__ int sortedv[CHUNK];
    __shared__ int gpos[CHUNK];
    int tid = threadIdx.x, blk = blockIdx.x;
    for (int i = tid; i < NBKT; i += 512) {
        cnt[i] = 0; cur[i] = 0;
        tg[i] = T[i];
    }
    __syncthreads();
    int e0 = blk * CHUNK, ee = min(e0 + CHUNK, NE);
    for (int i = e0 + tid; i < ee; i += 512) atomicAdd(&cnt[dst[i] >> 8], 1);
    __syncthreads();
    if (tid < 64) {
        excl_scan_lds(cnt, lst, NBKT, 7);
        excl_scan_lds(tg, bg, NBKT, 7);
    }
    __syncthreads();
    for (int i = tid; i < NBKT; i += 512) gbase[i] = bg[i] + O[(size_t)i * NBLK1 + blk];
    __syncthreads();
    for (int i = e0 + tid; i < ee; i += 512) {
        int d = dst[i];
        int b = d >> 8;
        int r = atomicAdd(&cur[b], 1);
        int t = lst[b] + r;
        sortedv[t] = (src[i] << 8) | (d & 255);
        gpos[t] = gbase[b] + r;
    }
    __syncthreads();
    int m = ee - e0;
    for (int t = tid; t < m; t += 512) bpacked[gpos[t]] = sortedv[t];
}

// one block per bucket: LDS counting sort by dst-local, emit srcp + rowptr
__global__ __launch_bounds__(512) void k_bsort(const int* __restrict__ T, const int* __restrict__ bpacked,
                                               int* __restrict__ srcp, int* __restrict__ rowptr) {
    __shared__ int ed[CAP3];
    __shared__ int cnt[256], lst[256], cur[256];
    __shared__ int tg[NBKT];
    __shared__ int bg[NBKT];
    int tid = threadIdx.x, b = blockIdx.x;
    if (b == 0 && tid < 64) srcp[NE + tid] = NN;   // sentinel pad for k_agg
    if (tid < 256) { cnt[tid] = 0; cur[tid] = 0; }
    for (int i = tid; i < NBKT; i += 512) tg[i] = T[i];
    __syncthreads();
    if (tid < 64) excl_scan_lds(tg, bg, NBKT, 7);
    __syncthreads();
    int ebeg = bg[b];
    int eend = (b + 1 < NBKT) ? bg[b + 1] : NE;
    int m = min(eend - ebeg, CAP3);
    for (int i = tid; i < m; i += 512) {
        int e = bpacked[ebeg + i];
        ed[i] = e;
        atomicAdd(&cnt[e & 255], 1);
    }
    __syncthreads();
    if (tid < 64) excl_scan_lds(cnt, lst, 256, 4);
    __syncthreads();
    if (tid < 256) {
        int gnode = b * 256 + tid;
        if (gnode < NN) rowptr[gnode] = ebeg + lst[tid];
    }
    if (b == NBKT - 1 && tid == 0) rowptr[NN] = NE;
    for (int i = tid; i < m; i += 512) {
        int e = ed[i];
        int dl = e & 255;
        int r = atomicAdd(&cur[dl], 1);
        srcp[ebeg + lst[dl] + r] = e >> 8;   // writes confined to this block's bucket window
    }
}

// ---------------- lin0: h0 = relu(x @ W0), [N,128]@[128,16] ----------------
__global__ __launch_bounds__(256) void k_lin0(const float* __restrict__ x, const float* __restrict__ w0,
                                              float* __restrict__ h0, int n) {
    __shared__ float xs[16 * 129];
    __shared__ float ws[128 * 16];
    int tid = threadIdx.x;
    int rowbase = blockIdx.x * 16;
    for (int j = tid; j < 2048; j += 256) ws[j] = w0[j];
    for (int j = tid; j < 2048; j += 256) {
        int r = j >> 7, c = j & 127;
        xs[r * 129 + c] = x[(size_t)rowbase * 128 + j];
    }
    __syncthreads();
    int rloc = tid >> 4, col = tid & 15;
    float acc = 0.f;
#pragma unroll 8
    for (int k = 0; k < 128; ++k) acc = fmaf(xs[rloc * 129 + k], ws[k * 16 + col], acc);
    h0[(size_t)rowbase * 16 + tid] = fmaxf(acc, 0.f);
}

// ---------------- layer-1 transforms + fused al: [N,16] -> HLb(bf16+al) + HR/SK(f32) ----------------
__global__ __launch_bounds__(384) void k_xform1(const float* __restrict__ h0,
                                                const float* __restrict__ wl, const float* __restrict__ bl,
                                                const float* __restrict__ wr, const float* __restrict__ br,
                                                const float* __restrict__ wf, const float* __restrict__ bf,
                                                const float* __restrict__ att,
                                                unsigned short* __restrict__ HLb, float* __restrict__ HR,
                                                float* __restrict__ SK, int n) {
    __shared__ float xT[16 * 68];
    int tx = threadIdx.x, ty = threadIdx.y;
    int t = ty * 96 + tx;
    int base = blockIdx.x * 64;
    for (int j = t; j < 64 * 16; j += 384) {
        int node = j >> 4, c = j & 15;
        float v = (base + node < n) ? h0[(size_t)base * 16 + j] : 0.f;
        xT[c * 68 + node] = v;
    }
    __syncthreads();
    float accl[16], accr[16], accf[16];
#pragma unroll
    for (int i = 0; i < 16; ++i) { accl[i] = 0.f; accr[i] = 0.f; accf[i] = 0.f; }
#pragma unroll 4
    for (int k = 0; k < 16; ++k) {
        float wlv = wl[k * 96 + tx], wrv = wr[k * 96 + tx], wfv = wf[k * 96 + tx];
        const float* row = xT + k * 68 + ty * 16;
        float4 x0 = *(const float4*)(row);
        float4 x1 = *(const float4*)(row + 4);
        float4 x2 = *(const float4*)(row + 8);
        float4 x3 = *(const float4*)(row + 12);
        float xv[16] = {x0.x,x0.y,x0.z,x0.w, x1.x,x1.y,x1.z,x1.w,
                        x2.x,x2.y,x2.z,x2.w, x3.x,x3.y,x3.z,x3.w};
#pragma unroll
        for (int i = 0; i < 16; ++i) {
            accl[i] = fmaf(xv[i], wlv, accl[i]);
            accr[i] = fmaf(xv[i], wrv, accr[i]);
            accf[i] = fmaf(xv[i], wfv, accf[i]);
        }
    }
    float blv = bl[tx], brv = br[tx], bfv = bf[tx];
    float attv = att[tx];
    int head = tx >> 5;   // 32-channel head groups are 32-lane aligned in this layout
#pragma unroll
    for (int i = 0; i < 16; ++i) {
        int node = base + ty * 16 + i;
        bool ok = node < n;
        float hlv = accl[i] + blv;
        if (ok) {
            HLb[(size_t)node * 128 + tx] = f2bf(hlv);
            HR[(size_t)node * 96 + tx] = accr[i] + brv;
            SK[(size_t)node * 96 + tx] = accf[i] + bfv;
        }
        float s = attv * hlv;
        s += __shfl_xor(s, 1); s += __shfl_xor(s, 2); s += __shfl_xor(s, 4);
        s += __shfl_xor(s, 8); s += __shfl_xor(s, 16);
        if (ok && (tx & 31) == i) {
            *(float*)((char*)HLb + ((size_t)node << 8) + 192 + 4 * head) = SCL06 * s;
        }
    }
}

// ---------------- layer-2 weight pack + dummy-sentinel-row init ----------------
__global__ __launch_bounds__(256) void k_prepw2(const float* __restrict__ wl, const float* __restrict__ wr,
                                                const float* __restrict__ wlast,
                                                unsigned short* __restrict__ bhi,
                                                unsigned short* __restrict__ blo,
                                                unsigned short* __restrict__ HLb) {
    int idx = blockIdx.x * 256 + threadIdx.x;   // 18 nt * 3 ks * 64 lanes = 3456 items
    if (idx >= 18 * 3 * 64) {
        // init sentinel row NN: channels = 0, al[0..3] = -1e30
        int q = idx - 3456;
        char* drow = (char*)HLb + ((size_t)NN << 8);
        if (q < 24) {
            ((uint2*)drow)[q] = uint2{0u, 0u};
        } else if (q < 28) {
            *(float*)(drow + 192 + 4 * (q - 24)) = -1e30f;
        }
        return;
    }
    int j = idx / 192;
    int s = (idx / 64) % 3;
    int l = idx & 63;
    int m = j / 6;
    int c = (j % 6) * 16 + (l & 15);
    const float* W = (m == 0) ? wl : (m == 1) ? wr : wlast;
    int k0 = s * 32 + (l >> 4) * 8;
#pragma unroll
    for (int u = 0; u < 8; ++u) {
        float v = W[(k0 + u) * 96 + c];
        unsigned short h = f2bf(v);
        float rf = v - __uint_as_float((unsigned)h << 16);
        bhi[idx * 8 + u] = h;
        blo[idx * 8 + u] = f2bf(rf);
    }
}

// C = h1[100000x96] @ B[96x288] + bias; HL out bf16+fused al, HR/SK fp32.
// Zero LDS/barriers; B frags reg-buffered; 4 independent MFMA chains.
__global__ __launch_bounds__(256) void k_xform2m(const float* __restrict__ h1,
        const unsigned short* __restrict__ bhi, const unsigned short* __restrict__ blo,
        const float* __restrict__ bl, const float* __restrict__ br, const float* __restrict__ blb,
        const float* __restrict__ att,
        unsigned short* __restrict__ HLb, float* __restrict__ HR, float* __restrict__ SK) {
    int tid = threadIdx.x;
    int wid = tid >> 6, lane = tid & 63;
    int rowbase = blockIdx.x * 64 + wid * 16;
    int arow = rowbase + (lane & 15);
    bool aval = (arow < NN);
    int kg = lane >> 4;
    const float* ap = h1 + (size_t)arow * 96 + kg * 8;

    // load + split A fragments: lane l holds A[l&15][s*32 + (l>>4)*8 + u]
    s16x8 ahi[3], alo[3];
#pragma unroll
    for (int s = 0; s < 3; ++s) {
        float av[8] = {0.f,0.f,0.f,0.f,0.f,0.f,0.f,0.f};
        if (aval) {
            float4 p0 = *(const float4*)(ap + s * 32);
            float4 p1 = *(const float4*)(ap + s * 32 + 4);
            av[0]=p0.x; av[1]=p0.y; av[2]=p0.z; av[3]=p0.w;
            av[4]=p1.x; av[5]=p1.y; av[6]=p1.z; av[7]=p1.w;
        }
#pragma unroll
        for (int u = 0; u < 8; ++u) {
            unsigned short h = f2bf(av[u]);
            float rf = av[u] - __uint_as_float((unsigned)h << 16);
            ahi[s][u] = (short)h;
            alo[s][u] = (short)f2bf(rf);
        }
    }

    const s16x8* BH = (const s16x8*)bhi;   // fragment (j,s): BH[(j*3+s)*64 + lane]
    const s16x8* BL = (const s16x8*)blo;
    int r0 = rowbase + (lane >> 4) * 4;
    int cl = lane & 15;

    s16x8 bh[3], bw[3], nbh[3], nbw[3];
#pragma unroll
    for (int s = 0; s < 3; ++s) {
        bh[s] = BH[s * 64 + lane];
        bw[s] = BL[s * 64 + lane];
    }

    float al0[4] = {0.f,0.f,0.f,0.f};
    float al1[4] = {0.f,0.f,0.f,0.f};
    float al2[4] = {0.f,0.f,0.f,0.f};

#pragma unroll
    for (int j = 0; j < 18; ++j) {
        if (j < 17) {
#pragma unroll
            for (int s = 0; s < 3; ++s) {
                nbh[s] = BH[((j + 1) * 3 + s) * 64 + lane];
                nbw[s] = BL[((j + 1) * 3 + s) * 64 + lane];
            }
        }
        f32x4 c00 = {0.f,0.f,0.f,0.f};
        f32x4 c01 = {0.f,0.f,0.f,0.f};
        f32x4 c10 = {0.f,0.f,0.f,0.f};
        f32x4 c11 = {0.f,0.f,0.f,0.f};
#pragma unroll
        for (int s = 0; s < 3; ++s) {
            c00 = __builtin_amdgcn_mfma_f32_16x16x32_bf16(ahi[s], bh[s], c00, 0, 0, 0);
            c01 = __builtin_amdgcn_mfma_f32_16x16x32_bf16(ahi[s], bw[s], c01, 0, 0, 0);
            c10 = __builtin_amdgcn_mfma_f32_16x16x32_bf16(alo[s], bh[s], c10, 0, 0, 0);
            c11 = __builtin_amdgcn_mfma_f32_16x16x32_bf16(alo[s], bw[s], c11, 0, 0, 0);
        }
        int m = j / 6;
        int c = (j % 6) * 16 + cl;
        if (m == 0) {
            float bv = bl[c];
            float attv = SCL06 * att[c];
#pragma unroll
            for (int r = 0; r < 4; ++r) {
                int row = r0 + r;
                float ov = c00[r] + c01[r] + c10[r] + c11[r] + bv;
                if (row < NN) HLb[(size_t)row * 128 + c] = f2bf(ov);
                if ((j >> 1) == 0)      al0[r] = fmaf(attv, ov, al0[r]);
                else if ((j >> 1) == 1) al1[r] = fmaf(attv, ov, al1[r]);
                else                    al2[r] = fmaf(attv, ov, al2[r]);
            }
            if (j == 5) {
#pragma unroll
                for (int r = 0; r < 4; ++r) {
                    float a0v = al0[r], a1v = al1[r], a2v = al2[r];
                    a0v += __shfl_xor(a0v, 1); a0v += __shfl_xor(a0v, 2);
                    a0v += __shfl_xor(a0v, 4); a0v += __shfl_xor(a0v, 8);
                    a1v += __shfl_xor(a1v, 1); a1v += __shfl_xor(a1v, 2);
                    a1v += __shfl_xor(a1v, 4); a1v += __shfl_xor(a1v, 8);
                    a2v += __shfl_xor(a2v, 1); a2v += __shfl_xor(a2v, 2);
                    a2v += __shfl_xor(a2v, 4); a2v += __shfl_xor(a2v, 8);
                    float sel = (cl == 0) ? a0v : (cl == 1) ? a1v : a2v;
                    int row = r0 + r;
                    if (cl < 3 && row < NN)
                        *(float*)((char*)HLb + ((size_t)row << 8) + 192 + 4 * cl) = sel;
                }
            }
        } else {
            const float* bp = (m == 1) ? br : blb;
            float* OP = (m == 1) ? HR : SK;
            float bv = bp[c];
#pragma unroll
            for (int r = 0; r < 4; ++r) {
                int row = r0 + r;
                if (row < NN) OP[(size_t)row * 96 + c] = c00[r] + c01[r] + c10[r] + c11[r] + bv;
            }
        }
#pragma unroll
        for (int s = 0; s < 3; ++s) { bh[s] = nbh[s]; bw[s] = nbw[s]; }
    }
}

// ---------------- GATv2 aggregation v7: 4 gather chains for MLP ----------------
// leaky_0.2(x) = 0.6x + 0.4|x| => score*log2e = arl + alv + sum((0.4 log2e att_c)|hr+hl|)
__global__ __launch_bounds__(256) void k_agg(const int* __restrict__ rowptr, const int* __restrict__ srcp,
                                             const unsigned short* __restrict__ HLb, const float* __restrict__ HR,
                                             const float* __restrict__ att, const float* __restrict__ bias,
                                             const float* __restrict__ SK, float* __restrict__ out,
                                             int n, int do_relu) {
    int node = (blockIdx.x * 256 + threadIdx.x) >> 6;
    int lane = threadIdx.x & 63;
    if (node >= n) return;
    int hl5 = lane & 31;
    int half = lane >> 5;
    bool active = hl5 < 24;
    int c = active ? 4 * hl5 : 92;
    const char* hlb8 = (const char*)HLb;
    unsigned coff = (unsigned)(2 * c);
    unsigned aoff = 192u + 4u * (unsigned)(hl5 >> 3);
    float4 hr = *(const float4*)(HR + (size_t)node * 96 + c);
    float4 atr = *(const float4*)(att + c);
    float4 at = {SCL04 * atr.x, SCL04 * atr.y, SCL04 * atr.z, SCL04 * atr.w};
    float ar = fmaf(atr.w, hr.w, fmaf(atr.z, hr.z, fmaf(atr.y, hr.y, atr.x * hr.x)));
    ar += __shfl_xor(ar, 1); ar += __shfl_xor(ar, 2); ar += __shfl_xor(ar, 4);
    float arl = SCL06 * ar;
    int beg = rowptr[node], end = rowptr[node + 1];
    float4 acc0 = {0.f,0.f,0.f,0.f}, acc1 = {0.f,0.f,0.f,0.f};
    float4 acc2 = {0.f,0.f,0.f,0.f}, acc3 = {0.f,0.f,0.f,0.f};
    float l0 = 0.f, l1 = 0.f, l2 = 0.f, l3 = 0.f;

#define EDGE(IDX, ACC, LACC) {                                           \
        int sj = __shfl(ss, (IDX), 64);                                  \
        unsigned bo = ((unsigned)sj) << 8;                               \
        uint2 u = *(const uint2*)(hlb8 + bo + coff);                     \
        float alv = *(const float*)(hlb8 + bo + aoff);                   \
        float ax = __uint_as_float(u.x << 16);                           \
        float ay = __uint_as_float(u.x & 0xffff0000u);                   \
        float az = __uint_as_float(u.y << 16);                           \
        float aw = __uint_as_float(u.y & 0xffff0000u);                   \
        float v0 = hr.x + ax, v1 = hr.y + ay;                            \
        float v2 = hr.z + az, v3 = hr.w + aw;                            \
        float ts = fmaf(fabsf(v3), at.w, fmaf(fabsf(v2), at.z,           \
                   fmaf(fabsf(v1), at.y, fabsf(v0) * at.x)));            \
        ts += __shfl_xor(ts, 1); ts += __shfl_xor(ts, 2);                \
        ts += __shfl_xor(ts, 4);                                         \
        float p = __builtin_amdgcn_exp2f(ts + arl + alv);                \
        LACC += p;                                                       \
        ACC.x = fmaf(p, ax, ACC.x); ACC.y = fmaf(p, ay, ACC.y);          \
        ACC.z = fmaf(p, az, ACC.z); ACC.w = fmaf(p, aw, ACC.w);          \
    }

    for (int cb = beg; cb < end; cb += 64) {
        int cnt = min(64, end - cb);
        int my = cb + lane;
        int ss = (my < end) ? srcp[my] : n;   // sentinel node n: al=-1e30 -> p=0
        int npair = (cnt + 1) >> 1;
        int np4 = (npair + 3) & ~3;           // sentinel absorbs over-run
        int idx = half;
        for (int j = 0; j < np4; j += 4) {
            EDGE(idx, acc0, l0)
            EDGE(idx + 2, acc1, l1)
            EDGE(idx + 4, acc2, l2)
            EDGE(idx + 6, acc3, l3)
            idx += 8;
        }
    }
#undef EDGE

    acc0.x += acc1.x + acc2.x + acc3.x;
    acc0.y += acc1.y + acc2.y + acc3.y;
    acc0.z += acc1.z + acc2.z + acc3.z;
    acc0.w += acc1.w + acc2.w + acc3.w;
    float l = l0 + l1 + l2 + l3;
    int partner = hl5 + 32;
    acc0.x += __shfl(acc0.x, partner, 64);
    acc0.y += __shfl(acc0.y, partner, 64);
    acc0.z += __shfl(acc0.z, partner, 64);
    acc0.w += __shfl(acc0.w, partner, 64);
    l      += __shfl(l, partner, 64);

    if (half == 0 && active) {
        float inv = 1.0f / (l + 1e-16f);
        size_t o = (size_t)node * 96 + c;
        float4 sk = *(const float4*)(SK + o);
        float4 bs = *(const float4*)(bias + c);
        float4 ov;
        ov.x = fmaf(acc0.x, inv, bs.x + sk.x);
        ov.y = fmaf(acc0.y, inv, bs.y + sk.y);
        ov.z = fmaf(acc0.z, inv, bs.z + sk.z);
        ov.w = fmaf(acc0.w, inv, bs.w + sk.w);
        if (do_relu) {
            ov.x = fmaxf(ov.x, 0.f); ov.y = fmaxf(ov.y, 0.f);
            ov.z = fmaxf(ov.z, 0.f); ov.w = fmaxf(ov.w, 0.f);
        }
        *(float4*)(out + o) = ov;
    }
}

extern "C" void kernel_launch(void* const* d_in, const int* in_sizes, int n_in,
                              void* d_out, int out_size, void* d_ws, size_t ws_size,
                              hipStream_t stream) {
    const float* x     = (const float*)d_in[0];
    const int*   ei    = (const int*)d_in[1];    // [2,E]: src = ei[0:E], dst = ei[E:2E]
    const float* W0    = (const float*)d_in[2];
    const float* Wl1   = (const float*)d_in[3];
    const float* bl1   = (const float*)d_in[4];
    const float* Wr1   = (const float*)d_in[5];
    const float* br1   = (const float*)d_in[6];
    const float* att1  = (const float*)d_in[7];
    const float* b1    = (const float*)d_in[8];
    const float* Wf    = (const float*)d_in[9];
    const float* bf    = (const float*)d_in[10];
    const float* Wl2   = (const float*)d_in[11];
    const float* bl2   = (const float*)d_in[12];
    const float* Wr2   = (const float*)d_in[13];
    const float* br2   = (const float*)d_in[14];
    const float* att2  = (const float*)d_in[15];
    const float* b2    = (const float*)d_in[16];
    const float* Wlast = (const float*)d_in[17];
    const float* blast = (const float*)d_in[18];

    const int* src = ei;
    const int* dst = ei + NE;

    size_t off = 0;
    auto carve = [&](size_t bytes) {
        void* p = (char*)d_ws + off;
        off += (bytes + 255) & ~(size_t)255;
        return p;
    };
    unsigned short* HLb = (unsigned short*)carve((size_t)(NN + 1) * 128 * 2);  // 256B rows: 96ch + 3 al + sentinel row
    float* HR  = (float*)carve((size_t)NN * 96 * 4);
    float* SK  = (float*)carve((size_t)NN * 96 * 4);
    float* H   = (float*)carve((size_t)NN * 96 * 4);   // h1; bpacked aliases this
    float* h0  = (float*)carve((size_t)NN * 16 * 4);
    int* rowptr  = (int*)carve((size_t)(NN + 1) * 4);
    int* srcp    = (int*)carve((size_t)(NE + 64) * 4);
    int* counts  = (int*)carve((size_t)NBKT * NBLK1 * 4);   // becomes O after k_bscan
    int* T       = (int*)carve((size_t)(NBKT + 8) * 4);     // bucket totals (unscanned)
    unsigned short* bhi2 = (unsigned short*)carve((size_t)18 * 3 * 64 * 8 * 2);
    unsigned short* blo2 = (unsigned short*)carve((size_t)18 * 3 * 64 * 8 * 2);
    int* bpacked = (int*)H;   // alias: dead before k_agg writes H
    (void)ws_size; (void)n_in; (void)in_sizes; (void)out_size;

    const int XF_BLOCKS = (NN + 63) / 64;          // 1563

    // CSR build (atomic-free at global scope, segmented scans, no serial kernel)
    k_bcount<<<NBLK1, 512, 0, stream>>>(dst, counts);
    k_bscan<<<NBKT, 512, 0, stream>>>(counts, T);
    k_bscatter<<<NBLK1, 512, 0, stream>>>(dst, src, counts, T, bpacked);
    k_bsort<<<NBKT, 512, 0, stream>>>(T, bpacked, srcp, rowptr);

    // pack layer-2 weights into MFMA fragments + init sentinel row (tiny)
    k_prepw2<<<14, 256, 0, stream>>>(Wl2, Wr2, Wlast, bhi2, blo2, HLb);

    // dense pipeline, layer 1
    k_lin0<<<NN / 16, 256, 0, stream>>>(x, W0, h0, NN);
    k_xform1<<<XF_BLOCKS, dim3(96, 4), 0, stream>>>(h0, Wl1, bl1, Wr1, br1, Wf, bf, att1, HLb, HR, SK, NN);
    k_agg<<<(NN + 3) / 4, 256, 0, stream>>>(rowptr, srcp, HLb, HR, att1, b1, SK, H, NN, 1);

    // layer 2 transforms: MFMA split-precision GEMM (no LDS, reg-resident B, fused al)
    k_xform2m<<<XF_BLOCKS, 256, 0, stream>>>(H, bhi2, blo2, bl2, br2, blast, att2, HLb, HR, SK);
    k_agg<<<(NN + 3) / 4, 256, 0, stream>>>(rowptr, srcp, HLb, HR, att2, b2, SK, (float*)d_out, NN, 0);
}

// Round 9
// 425.978 us; speedup vs baseline: 1.0183x; 1.0183x over previous
//
#include <hip/hip_runtime.h>
#include <cstdint>
#include <cfloat>

#define NN 100000
#define NE 1600000
#define NBKT 391          // buckets of 256 dst nodes: (NN+255)/256
#define CHUNK 4096
#define NBLK1 391         // ceil(NE/CHUNK)
#define CAP3 5120         // max edges per bucket (mean 4096, sigma ~64 -> 16 sigma)

typedef short s16x8 __attribute__((ext_vector_type(8)));
typedef float f32x4 __attribute__((ext_vector_type(4)));

#define SCL06 0.8656170245333781f   // 0.6 * log2(e)
#define SCL04 0.5770780163555854f   // 0.4 * log2(e)

__device__ __forceinline__ unsigned short f2bf(float v) {
    unsigned u = __float_as_uint(v);
    unsigned r = u + 0x7fffu + ((u >> 16) & 1u);
    return (unsigned short)(r >> 16);
}

// wave-0 exclusive scan of cnt[0..nelem) -> lst; caller guards threadIdx.x < 64
__device__ __forceinline__ void excl_scan_lds(const int* cnt, int* lst, int nelem, int per_lane) {
    int lane = threadIdx.x & 63;
    int base = lane * per_lane;
    int run = 0;
    int loc[16];
    for (int j = 0; j < per_lane; ++j) {
        int idx = base + j;
        loc[j] = run;
        if (idx < nelem) run += cnt[idx];
    }
    int tot = run;
    for (int off = 1; off < 64; off <<= 1) {
        int t = __shfl_up(tot, off);
        if (lane >= off) tot += t;
    }
    int pre = tot - run;
    for (int j = 0; j < per_lane; ++j) {
        int idx = base + j;
        if (idx < nelem) lst[idx] = pre + loc[j];
    }
}

// ---------------- CSR build: atomic-free bucket sort ----------------
__global__ __launch_bounds__(512) void k_bcount(const int* __restrict__ dst, int* __restrict__ counts) {
    __shared__ int h[NBKT];
    int tid = threadIdx.x, blk = blockIdx.x;
    for (int i = tid; i < NBKT; i += 512) h[i] = 0;
    __syncthreads();
    int e0 = blk * CHUNK, ee = min(e0 + CHUNK, NE);
    for (int i = e0 + tid; i < ee; i += 512) atomicAdd(&h[dst[i] >> 8], 1);
    __syncthreads();
    for (int i = tid; i < NBKT; i += 512) counts[i * NBLK1 + blk] = h[i];
}

// per-bucket segmented exclusive scan over chunks (in place) + bucket totals
__global__ __launch_bounds__(512) void k_bscan(int* __restrict__ counts, int* __restrict__ T) {
    __shared__ int row[NBLK1];
    __shared__ int lst[NBLK1];
    int b = blockIdx.x, tid = threadIdx.x;
    for (int i = tid; i < NBLK1; i += 512) row[i] = counts[(size_t)b * NBLK1 + i];
    __syncthreads();
    if (tid < 64) excl_scan_lds(row, lst, NBLK1, 7);
    __syncthreads();
    for (int i = tid; i < NBLK1; i += 512) counts[(size_t)b * NBLK1 + i] = lst[i];
    if (tid == 0) T[b] = lst[NBLK1 - 1] + row[NBLK1 - 1];
}

// re-read chunk, rank edges in LDS, reorder bucket-major, stream out packed words
// (scans bucket totals T in-LDS itself; no serial global scan kernel)
__global__ __launch_bounds__(512) void k_bscatter(const int* __restrict__ dst, const int* __restrict__ src,
                                                  const int* __restrict__ O, const int* __restrict__ T,
                                                  int* __restrict__ bpacked) {
    __shared__ int cnt[NBKT];
    __shared__ int lst[NBKT];
    __shared__ int cur[NBKT];
    __shared__ int gbase[NBKT];
    __shared__ int tg[NBKT];
    __shared__ int bg[NBKT];
    __shared__ int sortedv[CHUNK];
    __shared__ int gpos[CHUNK];
    int tid = threadIdx.x, blk = blockIdx.x;
    for (int i = tid; i < NBKT; i += 512) {
        cnt[i] = 0; cur[i] = 0;
        tg[i] = T[i];
    }
    __syncthreads();
    int e0 = blk * CHUNK, ee = min(e0 + CHUNK, NE);
    for (int i = e0 + tid; i < ee; i += 512) atomicAdd(&cnt[dst[i] >> 8], 1);
    __syncthreads();
    if (tid < 64) {
        excl_scan_lds(cnt, lst, NBKT, 7);
        excl_scan_lds(tg, bg, NBKT, 7);
    }
    __syncthreads();
    for (int i = tid; i < NBKT; i += 512) gbase[i] = bg[i] + O[(size_t)i * NBLK1 + blk];
    __syncthreads();
    for (int i = e0 + tid; i < ee; i += 512) {
        int d = dst[i];
        int b = d >> 8;
        int r = atomicAdd(&cur[b], 1);
        int t = lst[b] + r;
        sortedv[t] = (src[i] << 8) | (d & 255);
        gpos[t] = gbase[b] + r;
    }
    __syncthreads();
    int m = ee - e0;
    for (int t = tid; t < m; t += 512) bpacked[gpos[t]] = sortedv[t];
}

// one block per bucket: LDS counting sort by dst-local, emit srcp + rowptr
__global__ __launch_bounds__(512) void k_bsort(const int* __restrict__ T, const int* __restrict__ bpacked,
                                               int* __restrict__ srcp, int* __restrict__ rowptr) {
    __shared__ int ed[CAP3];
    __shared__ int cnt[256], lst[256], cur[256];
    __shared__ int tg[NBKT];
    __shared__ int bg[NBKT];
    int tid = threadIdx.x, b = blockIdx.x;
    if (b == 0 && tid < 64) srcp[NE + tid] = NN;   // sentinel pad for k_agg
    if (tid < 256) { cnt[tid] = 0; cur[tid] = 0; }
    for (int i = tid; i < NBKT; i += 512) tg[i] = T[i];
    __syncthreads();
    if (tid < 64) excl_scan_lds(tg, bg, NBKT, 7);
    __syncthreads();
    int ebeg = bg[b];
    int eend = (b + 1 < NBKT) ? bg[b + 1] : NE;
    int m = min(eend - ebeg, CAP3);
    for (int i = tid; i < m; i += 512) {
        int e = bpacked[ebeg + i];
        ed[i] = e;
        atomicAdd(&cnt[e & 255], 1);
    }
    __syncthreads();
    if (tid < 64) excl_scan_lds(cnt, lst, 256, 4);
    __syncthreads();
    if (tid < 256) {
        int gnode = b * 256 + tid;
        if (gnode < NN) rowptr[gnode] = ebeg + lst[tid];
    }
    if (b == NBKT - 1 && tid == 0) rowptr[NN] = NE;
    for (int i = tid; i < m; i += 512) {
        int e = ed[i];
        int dl = e & 255;
        int r = atomicAdd(&cur[dl], 1);
        srcp[ebeg + lst[dl] + r] = e >> 8;   // writes confined to this block's bucket window
    }
}

// ---------------- lin0: h0 = relu(x @ W0), [N,128]@[128,16] ----------------
__global__ __launch_bounds__(256) void k_lin0(const float* __restrict__ x, const float* __restrict__ w0,
                                              float* __restrict__ h0, int n) {
    __shared__ float xs[16 * 129];
    __shared__ float ws[128 * 16];
    int tid = threadIdx.x;
    int rowbase = blockIdx.x * 16;
    for (int j = tid; j < 2048; j += 256) ws[j] = w0[j];
    for (int j = tid; j < 2048; j += 256) {
        int r = j >> 7, c = j & 127;
        xs[r * 129 + c] = x[(size_t)rowbase * 128 + j];
    }
    __syncthreads();
    int rloc = tid >> 4, col = tid & 15;
    float acc = 0.f;
#pragma unroll 8
    for (int k = 0; k < 128; ++k) acc = fmaf(xs[rloc * 129 + k], ws[k * 16 + col], acc);
    h0[(size_t)rowbase * 16 + tid] = fmaxf(acc, 0.f);
}

// ---------------- layer-1 transforms + fused al: [N,16] -> HLb(bf16+al) + HR/SK(f32) ----------------
__global__ __launch_bounds__(384) void k_xform1(const float* __restrict__ h0,
                                                const float* __restrict__ wl, const float* __restrict__ bl,
                                                const float* __restrict__ wr, const float* __restrict__ br,
                                                const float* __restrict__ wf, const float* __restrict__ bf,
                                                const float* __restrict__ att,
                                                unsigned short* __restrict__ HLb, float* __restrict__ HR,
                                                float* __restrict__ SK, int n) {
    __shared__ float xT[16 * 68];
    int tx = threadIdx.x, ty = threadIdx.y;
    int t = ty * 96 + tx;
    int base = blockIdx.x * 64;
    for (int j = t; j < 64 * 16; j += 384) {
        int node = j >> 4, c = j & 15;
        float v = (base + node < n) ? h0[(size_t)base * 16 + j] : 0.f;
        xT[c * 68 + node] = v;
    }
    __syncthreads();
    float accl[16], accr[16], accf[16];
#pragma unroll
    for (int i = 0; i < 16; ++i) { accl[i] = 0.f; accr[i] = 0.f; accf[i] = 0.f; }
#pragma unroll 4
    for (int k = 0; k < 16; ++k) {
        float wlv = wl[k * 96 + tx], wrv = wr[k * 96 + tx], wfv = wf[k * 96 + tx];
        const float* row = xT + k * 68 + ty * 16;
        float4 x0 = *(const float4*)(row);
        float4 x1 = *(const float4*)(row + 4);
        float4 x2 = *(const float4*)(row + 8);
        float4 x3 = *(const float4*)(row + 12);
        float xv[16] = {x0.x,x0.y,x0.z,x0.w, x1.x,x1.y,x1.z,x1.w,
                        x2.x,x2.y,x2.z,x2.w, x3.x,x3.y,x3.z,x3.w};
#pragma unroll
        for (int i = 0; i < 16; ++i) {
            accl[i] = fmaf(xv[i], wlv, accl[i]);
            accr[i] = fmaf(xv[i], wrv, accr[i]);
            accf[i] = fmaf(xv[i], wfv, accf[i]);
        }
    }
    float blv = bl[tx], brv = br[tx], bfv = bf[tx];
    float attv = att[tx];
    int head = tx >> 5;   // 32-channel head groups are 32-lane aligned in this layout
#pragma unroll
    for (int i = 0; i < 16; ++i) {
        int node = base + ty * 16 + i;
        bool ok = node < n;
        float hlv = accl[i] + blv;
        if (ok) {
            HLb[(size_t)node * 128 + tx] = f2bf(hlv);
            HR[(size_t)node * 96 + tx] = accr[i] + brv;
            SK[(size_t)node * 96 + tx] = accf[i] + bfv;
        }
        float s = attv * hlv;
        s += __shfl_xor(s, 1); s += __shfl_xor(s, 2); s += __shfl_xor(s, 4);
        s += __shfl_xor(s, 8); s += __shfl_xor(s, 16);
        if (ok && (tx & 31) == i) {
            *(float*)((char*)HLb + ((size_t)node << 8) + 192 + 4 * head) = SCL06 * s;
        }
    }
}

// ---------------- layer-2 weight pack + dummy-sentinel-row init ----------------
__global__ __launch_bounds__(256) void k_prepw2(const float* __restrict__ wl, const float* __restrict__ wr,
                                                const float* __restrict__ wlast,
                                                unsigned short* __restrict__ bhi,
                                                unsigned short* __restrict__ blo,
                                                unsigned short* __restrict__ HLb) {
    int idx = blockIdx.x * 256 + threadIdx.x;   // 18 nt * 3 ks * 64 lanes = 3456 items
    if (idx >= 18 * 3 * 64) {
        // init sentinel row NN: channels = 0, al[0..3] = -1e30
        int q = idx - 3456;
        char* drow = (char*)HLb + ((size_t)NN << 8);
        if (q < 24) {
            ((uint2*)drow)[q] = uint2{0u, 0u};
        } else if (q < 28) {
            *(float*)(drow + 192 + 4 * (q - 24)) = -1e30f;
        }
        return;
    }
    int j = idx / 192;
    int s = (idx / 64) % 3;
    int l = idx & 63;
    int m = j / 6;
    int c = (j % 6) * 16 + (l & 15);
    const float* W = (m == 0) ? wl : (m == 1) ? wr : wlast;
    int k0 = s * 32 + (l >> 4) * 8;
#pragma unroll
    for (int u = 0; u < 8; ++u) {
        float v = W[(k0 + u) * 96 + c];
        unsigned short h = f2bf(v);
        float rf = v - __uint_as_float((unsigned)h << 16);
        bhi[idx * 8 + u] = h;
        blo[idx * 8 + u] = f2bf(rf);
    }
}

// C = h1[100000x96] @ B[96x288] + bias; HL out bf16+fused al, HR/SK fp32.
// Zero LDS/barriers; B frags reg-buffered; 4 independent MFMA chains.
__global__ __launch_bounds__(256) void k_xform2m(const float* __restrict__ h1,
        const unsigned short* __restrict__ bhi, const unsigned short* __restrict__ blo,
        const float* __restrict__ bl, const float* __restrict__ br, const float* __restrict__ blb,
        const float* __restrict__ att,
        unsigned short* __restrict__ HLb, float* __restrict__ HR, float* __restrict__ SK) {
    int tid = threadIdx.x;
    int wid = tid >> 6, lane = tid & 63;
    int rowbase = blockIdx.x * 64 + wid * 16;
    int arow = rowbase + (lane & 15);
    bool aval = (arow < NN);
    int kg = lane >> 4;
    const float* ap = h1 + (size_t)arow * 96 + kg * 8;

    // load + split A fragments: lane l holds A[l&15][s*32 + (l>>4)*8 + u]
    s16x8 ahi[3], alo[3];
#pragma unroll
    for (int s = 0; s < 3; ++s) {
        float av[8] = {0.f,0.f,0.f,0.f,0.f,0.f,0.f,0.f};
        if (aval) {
            float4 p0 = *(const float4*)(ap + s * 32);
            float4 p1 = *(const float4*)(ap + s * 32 + 4);
            av[0]=p0.x; av[1]=p0.y; av[2]=p0.z; av[3]=p0.w;
            av[4]=p1.x; av[5]=p1.y; av[6]=p1.z; av[7]=p1.w;
        }
#pragma unroll
        for (int u = 0; u < 8; ++u) {
            unsigned short h = f2bf(av[u]);
            float rf = av[u] - __uint_as_float((unsigned)h << 16);
            ahi[s][u] = (short)h;
            alo[s][u] = (short)f2bf(rf);
        }
    }

    const s16x8* BH = (const s16x8*)bhi;   // fragment (j,s): BH[(j*3+s)*64 + lane]
    const s16x8* BL = (const s16x8*)blo;
    int r0 = rowbase + (lane >> 4) * 4;
    int cl = lane & 15;

    s16x8 bh[3], bw[3], nbh[3], nbw[3];
#pragma unroll
    for (int s = 0; s < 3; ++s) {
        bh[s] = BH[s * 64 + lane];
        bw[s] = BL[s * 64 + lane];
    }

    float al0[4] = {0.f,0.f,0.f,0.f};
    float al1[4] = {0.f,0.f,0.f,0.f};
    float al2[4] = {0.f,0.f,0.f,0.f};

#pragma unroll
    for (int j = 0; j < 18; ++j) {
        if (j < 17) {
#pragma unroll
            for (int s = 0; s < 3; ++s) {
                nbh[s] = BH[((j + 1) * 3 + s) * 64 + lane];
                nbw[s] = BL[((j + 1) * 3 + s) * 64 + lane];
            }
        }
        f32x4 c00 = {0.f,0.f,0.f,0.f};
        f32x4 c01 = {0.f,0.f,0.f,0.f};
        f32x4 c10 = {0.f,0.f,0.f,0.f};
        f32x4 c11 = {0.f,0.f,0.f,0.f};
#pragma unroll
        for (int s = 0; s < 3; ++s) {
            c00 = __builtin_amdgcn_mfma_f32_16x16x32_bf16(ahi[s], bh[s], c00, 0, 0, 0);
            c01 = __builtin_amdgcn_mfma_f32_16x16x32_bf16(ahi[s], bw[s], c01, 0, 0, 0);
            c10 = __builtin_amdgcn_mfma_f32_16x16x32_bf16(alo[s], bh[s], c10, 0, 0, 0);
            c11 = __builtin_amdgcn_mfma_f32_16x16x32_bf16(alo[s], bw[s], c11, 0, 0, 0);
        }
        int m = j / 6;
        int c = (j % 6) * 16 + cl;
        if (m == 0) {
            float bv = bl[c];
            float attv = SCL06 * att[c];
#pragma unroll
            for (int r = 0; r < 4; ++r) {
                int row = r0 + r;
                float ov = c00[r] + c01[r] + c10[r] + c11[r] + bv;
                if (row < NN) HLb[(size_t)row * 128 + c] = f2bf(ov);
                if ((j >> 1) == 0)      al0[r] = fmaf(attv, ov, al0[r]);
                else if ((j >> 1) == 1) al1[r] = fmaf(attv, ov, al1[r]);
                else                    al2[r] = fmaf(attv, ov, al2[r]);
            }
            if (j == 5) {
#pragma unroll
                for (int r = 0; r < 4; ++r) {
                    float a0v = al0[r], a1v = al1[r], a2v = al2[r];
                    a0v += __shfl_xor(a0v, 1); a0v += __shfl_xor(a0v, 2);
                    a0v += __shfl_xor(a0v, 4); a0v += __shfl_xor(a0v, 8);
                    a1v += __shfl_xor(a1v, 1); a1v += __shfl_xor(a1v, 2);
                    a1v += __shfl_xor(a1v, 4); a1v += __shfl_xor(a1v, 8);
                    a2v += __shfl_xor(a2v, 1); a2v += __shfl_xor(a2v, 2);
                    a2v += __shfl_xor(a2v, 4); a2v += __shfl_xor(a2v, 8);
                    float sel = (cl == 0) ? a0v : (cl == 1) ? a1v : a2v;
                    int row = r0 + r;
                    if (cl < 3 && row < NN)
                        *(float*)((char*)HLb + ((size_t)row << 8) + 192 + 4 * cl) = sel;
                }
            }
        } else {
            const float* bp = (m == 1) ? br : blb;
            float* OP = (m == 1) ? HR : SK;
            float bv = bp[c];
#pragma unroll
            for (int r = 0; r < 4; ++r) {
                int row = r0 + r;
                if (row < NN) OP[(size_t)row * 96 + c] = c00[r] + c01[r] + c10[r] + c11[r] + bv;
            }
        }
#pragma unroll
        for (int s = 0; s < 3; ++s) { bh[s] = nbh[s]; bw[s] = nbw[s]; }
    }
}

// ---------------- GATv2 aggregation v6: sentinel edges + exp2 prescale (2-chain) ----------------
// leaky_0.2(x) = 0.6x + 0.4|x| => score*log2e = arl + alv + sum((0.4 log2e att_c)|hr+hl|)
__global__ __launch_bounds__(256) void k_agg(const int* __restrict__ rowptr, const int* __restrict__ srcp,
                                             const unsigned short* __restrict__ HLb, const float* __restrict__ HR,
                                             const float* __restrict__ att, const float* __restrict__ bias,
                                             const float* __restrict__ SK, float* __restrict__ out,
                                             int n, int do_relu) {
    int node = (blockIdx.x * 256 + threadIdx.x) >> 6;
    int lane = threadIdx.x & 63;
    if (node >= n) return;
    int hl5 = lane & 31;
    int half = lane >> 5;
    bool active = hl5 < 24;
    int c = active ? 4 * hl5 : 92;
    const char* hlb8 = (const char*)HLb;
    unsigned coff = (unsigned)(2 * c);
    unsigned aoff = 192u + 4u * (unsigned)(hl5 >> 3);
    float4 hr = *(const float4*)(HR + (size_t)node * 96 + c);
    float4 atr = *(const float4*)(att + c);
    float4 at = {SCL04 * atr.x, SCL04 * atr.y, SCL04 * atr.z, SCL04 * atr.w};
    float ar = fmaf(atr.w, hr.w, fmaf(atr.z, hr.z, fmaf(atr.y, hr.y, atr.x * hr.x)));
    ar += __shfl_xor(ar, 1); ar += __shfl_xor(ar, 2); ar += __shfl_xor(ar, 4);
    float arl = SCL06 * ar;
    int beg = rowptr[node], end = rowptr[node + 1];
    float4 acc0 = {0.f,0.f,0.f,0.f}, acc1 = {0.f,0.f,0.f,0.f};
    float l0 = 0.f, l1 = 0.f;

#define EDGE(IDX, ACC, LACC) {                                           \
        int sj = __shfl(ss, (IDX), 64);                                  \
        unsigned bo = ((unsigned)sj) << 8;                               \
        uint2 u = *(const uint2*)(hlb8 + bo + coff);                     \
        float alv = *(const float*)(hlb8 + bo + aoff);                   \
        float ax = __uint_as_float(u.x << 16);                           \
        float ay = __uint_as_float(u.x & 0xffff0000u);                   \
        float az = __uint_as_float(u.y << 16);                           \
        float aw = __uint_as_float(u.y & 0xffff0000u);                   \
        float v0 = hr.x + ax, v1 = hr.y + ay;                            \
        float v2 = hr.z + az, v3 = hr.w + aw;                            \
        float ts = fmaf(fabsf(v3), at.w, fmaf(fabsf(v2), at.z,           \
                   fmaf(fabsf(v1), at.y, fabsf(v0) * at.x)));            \
        ts += __shfl_xor(ts, 1); ts += __shfl_xor(ts, 2);                \
        ts += __shfl_xor(ts, 4);                                         \
        float p = __builtin_amdgcn_exp2f(ts + arl + alv);                \
        LACC += p;                                                       \
        ACC.x = fmaf(p, ax, ACC.x); ACC.y = fmaf(p, ay, ACC.y);          \
        ACC.z = fmaf(p, az, ACC.z); ACC.w = fmaf(p, aw, ACC.w);          \
    }

    for (int cb = beg; cb < end; cb += 64) {
        int cnt = min(64, end - cb);
        int my = cb + lane;
        int ss = (my < end) ? srcp[my] : n;   // sentinel node n: al=-1e30 -> p=0
        int npair = (cnt + 1) >> 1;
        int idx = half;
        int j = 0;
        for (; j + 2 <= npair; j += 2) {
            EDGE(idx, acc0, l0)
            EDGE(idx + 2, acc1, l1)
            idx += 4;
        }
        if (j < npair) EDGE(idx, acc0, l0)
    }
#undef EDGE

    acc0.x += acc1.x; acc0.y += acc1.y; acc0.z += acc1.z; acc0.w += acc1.w;
    float l = l0 + l1;
    int partner = hl5 + 32;
    acc0.x += __shfl(acc0.x, partner, 64);
    acc0.y += __shfl(acc0.y, partner, 64);
    acc0.z += __shfl(acc0.z, partner, 64);
    acc0.w += __shfl(acc0.w, partner, 64);
    l      += __shfl(l, partner, 64);

    if (half == 0 && active) {
        float inv = 1.0f / (l + 1e-16f);
        size_t o = (size_t)node * 96 + c;
        float4 sk = *(const float4*)(SK + o);
        float4 bs = *(const float4*)(bias + c);
        float4 ov;
        ov.x = fmaf(acc0.x, inv, bs.x + sk.x);
        ov.y = fmaf(acc0.y, inv, bs.y + sk.y);
        ov.z = fmaf(acc0.z, inv, bs.z + sk.z);
        ov.w = fmaf(acc0.w, inv, bs.w + sk.w);
        if (do_relu) {
            ov.x = fmaxf(ov.x, 0.f); ov.y = fmaxf(ov.y, 0.f);
            ov.z = fmaxf(ov.z, 0.f); ov.w = fmaxf(ov.w, 0.f);
        }
        *(float4*)(out + o) = ov;
    }
}

extern "C" void kernel_launch(void* const* d_in, const int* in_sizes, int n_in,
                              void* d_out, int out_size, void* d_ws, size_t ws_size,
                              hipStream_t stream) {
    const float* x     = (const float*)d_in[0];
    const int*   ei    = (const int*)d_in[1];    // [2,E]: src = ei[0:E], dst = ei[E:2E]
    const float* W0    = (const float*)d_in[2];
    const float* Wl1   = (const float*)d_in[3];
    const float* bl1   = (const float*)d_in[4];
    const float* Wr1   = (const float*)d_in[5];
    const float* br1   = (const float*)d_in[6];
    const float* att1  = (const float*)d_in[7];
    const float* b1    = (const float*)d_in[8];
    const float* Wf    = (const float*)d_in[9];
    const float* bf    = (const float*)d_in[10];
    const float* Wl2   = (const float*)d_in[11];
    const float* bl2   = (const float*)d_in[12];
    const float* Wr2   = (const float*)d_in[13];
    const float* br2   = (const float*)d_in[14];
    const float* att2  = (const float*)d_in[15];
    const float* b2    = (const float*)d_in[16];
    const float* Wlast = (const float*)d_in[17];
    const float* blast = (const float*)d_in[18];

    const int* src = ei;
    const int* dst = ei + NE;

    size_t off = 0;
    auto carve = [&](size_t bytes) {
        void* p = (char*)d_ws + off;
        off += (bytes + 255) & ~(size_t)255;
        return p;
    };
    unsigned short* HLb = (unsigned short*)carve((size_t)(NN + 1) * 128 * 2);  // 256B rows: 96ch + 3 al + sentinel row
    float* HR  = (float*)carve((size_t)NN * 96 * 4);
    float* SK  = (float*)carve((size_t)NN * 96 * 4);
    float* H   = (float*)carve((size_t)NN * 96 * 4);   // h1; bpacked aliases this
    float* h0  = (float*)carve((size_t)NN * 16 * 4);
    int* rowptr  = (int*)carve((size_t)(NN + 1) * 4);
    int* srcp    = (int*)carve((size_t)(NE + 64) * 4);
    int* counts  = (int*)carve((size_t)NBKT * NBLK1 * 4);   // becomes O after k_bscan
    int* T       = (int*)carve((size_t)(NBKT + 8) * 4);     // bucket totals (unscanned)
    unsigned short* bhi2 = (unsigned short*)carve((size_t)18 * 3 * 64 * 8 * 2);
    unsigned short* blo2 = (unsigned short*)carve((size_t)18 * 3 * 64 * 8 * 2);
    int* bpacked = (int*)H;   // alias: dead before k_agg writes H
    (void)ws_size; (void)n_in; (void)in_sizes; (void)out_size;

    const int XF_BLOCKS = (NN + 63) / 64;          // 1563

    // CSR build (atomic-free at global scope, segmented scans, no serial kernel)
    k_bcount<<<NBLK1, 512, 0, stream>>>(dst, counts);
    k_bscan<<<NBKT, 512, 0, stream>>>(counts, T);
    k_bscatter<<<NBLK1, 512, 0, stream>>>(dst, src, counts, T, bpacked);
    k_bsort<<<NBKT, 512, 0, stream>>>(T, bpacked, srcp, rowptr);

    // pack layer-2 weights into MFMA fragments + init sentinel row (tiny)
    k_prepw2<<<14, 256, 0, stream>>>(Wl2, Wr2, Wlast, bhi2, blo2, HLb);

    // dense pipeline, layer 1
    k_lin0<<<NN / 16, 256, 0, stream>>>(x, W0, h0, NN);
    k_xform1<<<XF_BLOCKS, dim3(96, 4), 0, stream>>>(h0, Wl1, bl1, Wr1, br1, Wf, bf, att1, HLb, HR, SK, NN);
    k_agg<<<(NN + 3) / 4, 256, 0, stream>>>(rowptr, srcp, HLb, HR, att1, b1, SK, H, NN, 1);

    // layer 2 transforms: MFMA split-precision GEMM (no LDS, reg-resident B, fused al)
    k_xform2m<<<XF_BLOCKS, 256, 0, stream>>>(H, bhi2, blo2, bl2, br2, blast, att2, HLb, HR, SK);
    k_agg<<<(NN + 3) / 4, 256, 0, stream>>>(rowptr, srcp, HLb, HR, att2, b2, SK, (float*)d_out, NN, 0);
}

// Round 10
// 422.674 us; speedup vs baseline: 1.0262x; 1.0078x over previous
//
#include <hip/hip_runtime.h>
#include <cstdint>
#include <cfloat>

#define NN 100000
#define NE 1600000
#define NBKT 391          // buckets of 256 dst nodes: (NN+255)/256
#define CHUNK 4096
#define NBLK1 391         // ceil(NE/CHUNK)
#define CAP3 5120         // max edges per bucket (mean 4096, sigma ~64 -> 16 sigma)

typedef short s16x8 __attribute__((ext_vector_type(8)));
typedef float f32x4 __attribute__((ext_vector_type(4)));

#define SCL06 0.8656170245333781f   // 0.6 * log2(e)
#define SCL04 0.5770780163555854f   // 0.4 * log2(e)

__device__ __forceinline__ unsigned short f2bf(float v) {
    unsigned u = __float_as_uint(v);
    unsigned r = u + 0x7fffu + ((u >> 16) & 1u);
    return (unsigned short)(r >> 16);
}

// wave-0 exclusive scan of cnt[0..nelem) -> lst; caller guards threadIdx.x < 64
__device__ __forceinline__ void excl_scan_lds(const int* cnt, int* lst, int nelem, int per_lane) {
    int lane = threadIdx.x & 63;
    int base = lane * per_lane;
    int run = 0;
    int loc[16];
    for (int j = 0; j < per_lane; ++j) {
        int idx = base + j;
        loc[j] = run;
        if (idx < nelem) run += cnt[idx];
    }
    int tot = run;
    for (int off = 1; off < 64; off <<= 1) {
        int t = __shfl_up(tot, off);
        if (lane >= off) tot += t;
    }
    int pre = tot - run;
    for (int j = 0; j < per_lane; ++j) {
        int idx = base + j;
        if (idx < nelem) lst[idx] = pre + loc[j];
    }
}

// ---------------- CSR build v3: single-pass atomic-reservation bucket scatter ----------------
// Each chunk block counts per-bucket, reserves a range in each bucket's arena slab via ONE
// atomicAdd per (block,bucket), then streams its LDS-reordered edges out. cur_g ends up
// holding exact per-bucket degrees (=T), which k_bsort scans in-LDS for rowptr bases.
__global__ __launch_bounds__(512) void k_bscat(const int* __restrict__ dst, const int* __restrict__ src,
                                               int* __restrict__ cur_g, int* __restrict__ arena) {
    __shared__ int cnt[NBKT];
    __shared__ int lst[NBKT];
    __shared__ int pos[NBKT];
    __shared__ int loc[NBKT];
    __shared__ int sortedv[CHUNK];
    __shared__ int gpos[CHUNK];
    int tid = threadIdx.x, blk = blockIdx.x;
    for (int i = tid; i < NBKT; i += 512) { cnt[i] = 0; loc[i] = 0; }
    __syncthreads();
    int e0 = blk * CHUNK, ee = min(e0 + CHUNK, NE);
    for (int i = e0 + tid; i < ee; i += 512) atomicAdd(&cnt[dst[i] >> 8], 1);
    __syncthreads();
    if (tid < 64) excl_scan_lds(cnt, lst, NBKT, 7);
    __syncthreads();
    for (int i = tid; i < NBKT; i += 512) {
        int c = cnt[i];
        pos[i] = c ? atomicAdd(&cur_g[i], c) : 0;
    }
    __syncthreads();
    for (int i = e0 + tid; i < ee; i += 512) {
        int d = dst[i];
        int b = d >> 8;
        int r = atomicAdd(&loc[b], 1);
        int t = lst[b] + r;
        sortedv[t] = (src[i] << 8) | (d & 255);
        int g = pos[b] + r;
        gpos[t] = (g < CAP3) ? b * CAP3 + g : -1;   // overflow guard (16-sigma)
    }
    __syncthreads();
    int m = ee - e0;
    for (int t = tid; t < m; t += 512) {
        int g = gpos[t];
        if (g >= 0) arena[g] = sortedv[t];
    }
}

// one block per bucket: in-LDS scan of degrees -> rowptr base; LDS counting sort by
// dst-local; emit srcp + rowptr
__global__ __launch_bounds__(512) void k_bsort(const int* __restrict__ T, const int* __restrict__ arena,
                                               int* __restrict__ srcp, int* __restrict__ rowptr) {
    __shared__ int ed[CAP3];
    __shared__ int cnt[256], lst[256], cur[256];
    __shared__ int tg[NBKT];
    __shared__ int bg[NBKT];
    int tid = threadIdx.x, b = blockIdx.x;
    if (b == 0 && tid < 64) srcp[NE + tid] = NN;   // sentinel pad for k_agg
    if (tid < 256) { cnt[tid] = 0; cur[tid] = 0; }
    for (int i = tid; i < NBKT; i += 512) tg[i] = T[i];
    __syncthreads();
    if (tid < 64) excl_scan_lds(tg, bg, NBKT, 7);
    __syncthreads();
    int ebeg = bg[b];
    int m = min(tg[b], CAP3);
    const int* win = arena + (size_t)b * CAP3;
    for (int i = tid; i < m; i += 512) {
        int e = win[i];
        ed[i] = e;
        atomicAdd(&cnt[e & 255], 1);
    }
    __syncthreads();
    if (tid < 64) excl_scan_lds(cnt, lst, 256, 4);
    __syncthreads();
    if (tid < 256) {
        int gnode = b * 256 + tid;
        if (gnode < NN) rowptr[gnode] = ebeg + lst[tid];
    }
    if (b == NBKT - 1 && tid == 0) rowptr[NN] = NE;
    for (int i = tid; i < m; i += 512) {
        int e = ed[i];
        int dl = e & 255;
        int r = atomicAdd(&cur[dl], 1);
        srcp[ebeg + lst[dl] + r] = e >> 8;   // writes confined to this block's bucket window
    }
}

// ---------------- lin0: h0 = relu(x @ W0), [N,128]@[128,16] ----------------
__global__ __launch_bounds__(256) void k_lin0(const float* __restrict__ x, const float* __restrict__ w0,
                                              float* __restrict__ h0, int n) {
    __shared__ float xs[16 * 129];
    __shared__ float ws[128 * 16];
    int tid = threadIdx.x;
    int rowbase = blockIdx.x * 16;
    for (int j = tid; j < 2048; j += 256) ws[j] = w0[j];
    for (int j = tid; j < 2048; j += 256) {
        int r = j >> 7, c = j & 127;
        xs[r * 129 + c] = x[(size_t)rowbase * 128 + j];
    }
    __syncthreads();
    int rloc = tid >> 4, col = tid & 15;
    float acc = 0.f;
#pragma unroll 8
    for (int k = 0; k < 128; ++k) acc = fmaf(xs[rloc * 129 + k], ws[k * 16 + col], acc);
    h0[(size_t)rowbase * 16 + tid] = fmaxf(acc, 0.f);
}

// ---------------- layer-1 transforms + fused al: [N,16] -> HLb(bf16+al) + HRb(bf16) + SK(f32) ----------------
__global__ __launch_bounds__(384) void k_xform1(const float* __restrict__ h0,
                                                const float* __restrict__ wl, const float* __restrict__ bl,
                                                const float* __restrict__ wr, const float* __restrict__ br,
                                                const float* __restrict__ wf, const float* __restrict__ bf,
                                                const float* __restrict__ att,
                                                unsigned short* __restrict__ HLb, unsigned short* __restrict__ HRb,
                                                float* __restrict__ SK, int n) {
    __shared__ float xT[16 * 68];
    int tx = threadIdx.x, ty = threadIdx.y;
    int t = ty * 96 + tx;
    int base = blockIdx.x * 64;
    for (int j = t; j < 64 * 16; j += 384) {
        int node = j >> 4, c = j & 15;
        float v = (base + node < n) ? h0[(size_t)base * 16 + j] : 0.f;
        xT[c * 68 + node] = v;
    }
    __syncthreads();
    float accl[16], accr[16], accf[16];
#pragma unroll
    for (int i = 0; i < 16; ++i) { accl[i] = 0.f; accr[i] = 0.f; accf[i] = 0.f; }
#pragma unroll 4
    for (int k = 0; k < 16; ++k) {
        float wlv = wl[k * 96 + tx], wrv = wr[k * 96 + tx], wfv = wf[k * 96 + tx];
        const float* row = xT + k * 68 + ty * 16;
        float4 x0 = *(const float4*)(row);
        float4 x1 = *(const float4*)(row + 4);
        float4 x2 = *(const float4*)(row + 8);
        float4 x3 = *(const float4*)(row + 12);
        float xv[16] = {x0.x,x0.y,x0.z,x0.w, x1.x,x1.y,x1.z,x1.w,
                        x2.x,x2.y,x2.z,x2.w, x3.x,x3.y,x3.z,x3.w};
#pragma unroll
        for (int i = 0; i < 16; ++i) {
            accl[i] = fmaf(xv[i], wlv, accl[i]);
            accr[i] = fmaf(xv[i], wrv, accr[i]);
            accf[i] = fmaf(xv[i], wfv, accf[i]);
        }
    }
    float blv = bl[tx], brv = br[tx], bfv = bf[tx];
    float attv = att[tx];
    int head = tx >> 5;   // 32-channel head groups are 32-lane aligned in this layout
#pragma unroll
    for (int i = 0; i < 16; ++i) {
        int node = base + ty * 16 + i;
        bool ok = node < n;
        float hlv = accl[i] + blv;
        if (ok) {
            HLb[(size_t)node * 128 + tx] = f2bf(hlv);
            HRb[(size_t)node * 96 + tx] = f2bf(accr[i] + brv);
            SK[(size_t)node * 96 + tx] = accf[i] + bfv;
        }
        float s = attv * hlv;
        s += __shfl_xor(s, 1); s += __shfl_xor(s, 2); s += __shfl_xor(s, 4);
        s += __shfl_xor(s, 8); s += __shfl_xor(s, 16);
        if (ok && (tx & 31) == i) {
            *(float*)((char*)HLb + ((size_t)node << 8) + 192 + 4 * head) = SCL06 * s;
        }
    }
}

// ---------------- layer-2 weight pack + dummy-sentinel-row init ----------------
__global__ __launch_bounds__(256) void k_prepw2(const float* __restrict__ wl, const float* __restrict__ wr,
                                                const float* __restrict__ wlast,
                                                unsigned short* __restrict__ bhi,
                                                unsigned short* __restrict__ blo,
                                                unsigned short* __restrict__ HLb) {
    int idx = blockIdx.x * 256 + threadIdx.x;   // 18 nt * 3 ks * 64 lanes = 3456 items
    if (idx >= 18 * 3 * 64) {
        // init sentinel row NN: channels = 0, al[0..3] = -1e30
        int q = idx - 3456;
        char* drow = (char*)HLb + ((size_t)NN << 8);
        if (q < 24) {
            ((uint2*)drow)[q] = uint2{0u, 0u};
        } else if (q < 28) {
            *(float*)(drow + 192 + 4 * (q - 24)) = -1e30f;
        }
        return;
    }
    int j = idx / 192;
    int s = (idx / 64) % 3;
    int l = idx & 63;
    int m = j / 6;
    int c = (j % 6) * 16 + (l & 15);
    const float* W = (m == 0) ? wl : (m == 1) ? wr : wlast;
    int k0 = s * 32 + (l >> 4) * 8;
#pragma unroll
    for (int u = 0; u < 8; ++u) {
        float v = W[(k0 + u) * 96 + c];
        unsigned short h = f2bf(v);
        float rf = v - __uint_as_float((unsigned)h << 16);
        bhi[idx * 8 + u] = h;
        blo[idx * 8 + u] = f2bf(rf);
    }
}

// C = h1[100000x96] @ B[96x288] + bias; HL out bf16+fused al, HR bf16, SK fp32.
// Zero LDS/barriers; B frags reg-buffered; 4 independent MFMA chains.
__global__ __launch_bounds__(256) void k_xform2m(const float* __restrict__ h1,
        const unsigned short* __restrict__ bhi, const unsigned short* __restrict__ blo,
        const float* __restrict__ bl, const float* __restrict__ br, const float* __restrict__ blb,
        const float* __restrict__ att,
        unsigned short* __restrict__ HLb, unsigned short* __restrict__ HRb, float* __restrict__ SK) {
    int tid = threadIdx.x;
    int wid = tid >> 6, lane = tid & 63;
    int rowbase = blockIdx.x * 64 + wid * 16;
    int arow = rowbase + (lane & 15);
    bool aval = (arow < NN);
    int kg = lane >> 4;
    const float* ap = h1 + (size_t)arow * 96 + kg * 8;

    // load + split A fragments: lane l holds A[l&15][s*32 + (l>>4)*8 + u]
    s16x8 ahi[3], alo[3];
#pragma unroll
    for (int s = 0; s < 3; ++s) {
        float av[8] = {0.f,0.f,0.f,0.f,0.f,0.f,0.f,0.f};
        if (aval) {
            float4 p0 = *(const float4*)(ap + s * 32);
            float4 p1 = *(const float4*)(ap + s * 32 + 4);
            av[0]=p0.x; av[1]=p0.y; av[2]=p0.z; av[3]=p0.w;
            av[4]=p1.x; av[5]=p1.y; av[6]=p1.z; av[7]=p1.w;
        }
#pragma unroll
        for (int u = 0; u < 8; ++u) {
            unsigned short h = f2bf(av[u]);
            float rf = av[u] - __uint_as_float((unsigned)h << 16);
            ahi[s][u] = (short)h;
            alo[s][u] = (short)f2bf(rf);
        }
    }

    const s16x8* BH = (const s16x8*)bhi;   // fragment (j,s): BH[(j*3+s)*64 + lane]
    const s16x8* BL = (const s16x8*)blo;
    int r0 = rowbase + (lane >> 4) * 4;
    int cl = lane & 15;

    s16x8 bh[3], bw[3], nbh[3], nbw[3];
#pragma unroll
    for (int s = 0; s < 3; ++s) {
        bh[s] = BH[s * 64 + lane];
        bw[s] = BL[s * 64 + lane];
    }

    float al0[4] = {0.f,0.f,0.f,0.f};
    float al1[4] = {0.f,0.f,0.f,0.f};
    float al2[4] = {0.f,0.f,0.f,0.f};

#pragma unroll
    for (int j = 0; j < 18; ++j) {
        if (j < 17) {
#pragma unroll
            for (int s = 0; s < 3; ++s) {
                nbh[s] = BH[((j + 1) * 3 + s) * 64 + lane];
                nbw[s] = BL[((j + 1) * 3 + s) * 64 + lane];
            }
        }
        f32x4 c00 = {0.f,0.f,0.f,0.f};
        f32x4 c01 = {0.f,0.f,0.f,0.f};
        f32x4 c10 = {0.f,0.f,0.f,0.f};
        f32x4 c11 = {0.f,0.f,0.f,0.f};
#pragma unroll
        for (int s = 0; s < 3; ++s) {
            c00 = __builtin_amdgcn_mfma_f32_16x16x32_bf16(ahi[s], bh[s], c00, 0, 0, 0);
            c01 = __builtin_amdgcn_mfma_f32_16x16x32_bf16(ahi[s], bw[s], c01, 0, 0, 0);
            c10 = __builtin_amdgcn_mfma_f32_16x16x32_bf16(alo[s], bh[s], c10, 0, 0, 0);
            c11 = __builtin_amdgcn_mfma_f32_16x16x32_bf16(alo[s], bw[s], c11, 0, 0, 0);
        }
        int m = j / 6;
        int c = (j % 6) * 16 + cl;
        if (m == 0) {
            float bv = bl[c];
            float attv = SCL06 * att[c];
#pragma unroll
            for (int r = 0; r < 4; ++r) {
                int row = r0 + r;
                float ov = c00[r] + c01[r] + c10[r] + c11[r] + bv;
                if (row < NN) HLb[(size_t)row * 128 + c] = f2bf(ov);
                if ((j >> 1) == 0)      al0[r] = fmaf(attv, ov, al0[r]);
                else if ((j >> 1) == 1) al1[r] = fmaf(attv, ov, al1[r]);
                else                    al2[r] = fmaf(attv, ov, al2[r]);
            }
            if (j == 5) {
#pragma unroll
                for (int r = 0; r < 4; ++r) {
                    float a0v = al0[r], a1v = al1[r], a2v = al2[r];
                    a0v += __shfl_xor(a0v, 1); a0v += __shfl_xor(a0v, 2);
                    a0v += __shfl_xor(a0v, 4); a0v += __shfl_xor(a0v, 8);
                    a1v += __shfl_xor(a1v, 1); a1v += __shfl_xor(a1v, 2);
                    a1v += __shfl_xor(a1v, 4); a1v += __shfl_xor(a1v, 8);
                    a2v += __shfl_xor(a2v, 1); a2v += __shfl_xor(a2v, 2);
                    a2v += __shfl_xor(a2v, 4); a2v += __shfl_xor(a2v, 8);
                    float sel = (cl == 0) ? a0v : (cl == 1) ? a1v : a2v;
                    int row = r0 + r;
                    if (cl < 3 && row < NN)
                        *(float*)((char*)HLb + ((size_t)row << 8) + 192 + 4 * cl) = sel;
                }
            }
        } else if (m == 1) {
            float bv = br[c];
#pragma unroll
            for (int r = 0; r < 4; ++r) {
                int row = r0 + r;
                if (row < NN) HRb[(size_t)row * 96 + c] = f2bf(c00[r] + c01[r] + c10[r] + c11[r] + bv);
            }
        } else {
            float bv = blb[c];
#pragma unroll
            for (int r = 0; r < 4; ++r) {
                int row = r0 + r;
                if (row < NN) SK[(size_t)row * 96 + c] = c00[r] + c01[r] + c10[r] + c11[r] + bv;
            }
        }
#pragma unroll
        for (int s = 0; s < 3; ++s) { bh[s] = nbh[s]; bw[s] = nbw[s]; }
    }
}

// ---------------- GATv2 aggregation v8: bf16 HR + sentinel edges + exp2 prescale ----------------
// leaky_0.2(x) = 0.6x + 0.4|x| => score*log2e = arl + alv + sum((0.4 log2e att_c)|hr+hl|)
__global__ __launch_bounds__(256) void k_agg(const int* __restrict__ rowptr, const int* __restrict__ srcp,
                                             const unsigned short* __restrict__ HLb, const unsigned short* __restrict__ HRb,
                                             const float* __restrict__ att, const float* __restrict__ bias,
                                             const float* __restrict__ SK, float* __restrict__ out,
                                             int n, int do_relu) {
    int node = (blockIdx.x * 256 + threadIdx.x) >> 6;
    int lane = threadIdx.x & 63;
    if (node >= n) return;
    int hl5 = lane & 31;
    int half = lane >> 5;
    bool active = hl5 < 24;
    int c = active ? 4 * hl5 : 92;
    const char* hlb8 = (const char*)HLb;
    unsigned coff = (unsigned)(2 * c);
    unsigned aoff = 192u + 4u * (unsigned)(hl5 >> 3);
    uint2 uh = *(const uint2*)(HRb + (size_t)node * 96 + c);
    float4 hr;
    hr.x = __uint_as_float(uh.x << 16);
    hr.y = __uint_as_float(uh.x & 0xffff0000u);
    hr.z = __uint_as_float(uh.y << 16);
    hr.w = __uint_as_float(uh.y & 0xffff0000u);
    float4 atr = *(const float4*)(att + c);
    float4 at = {SCL04 * atr.x, SCL04 * atr.y, SCL04 * atr.z, SCL04 * atr.w};
    float ar = fmaf(atr.w, hr.w, fmaf(atr.z, hr.z, fmaf(atr.y, hr.y, atr.x * hr.x)));
    ar += __shfl_xor(ar, 1); ar += __shfl_xor(ar, 2); ar += __shfl_xor(ar, 4);
    float arl = SCL06 * ar;
    int beg = rowptr[node], end = rowptr[node + 1];
    float4 acc0 = {0.f,0.f,0.f,0.f}, acc1 = {0.f,0.f,0.f,0.f};
    float l0 = 0.f, l1 = 0.f;

#define EDGE(IDX, ACC, LACC) {                                           \
        int sj = __shfl(ss, (IDX), 64);                                  \
        unsigned bo = ((unsigned)sj) << 8;                               \
        uint2 u = *(const uint2*)(hlb8 + bo + coff);                     \
        float alv = *(const float*)(hlb8 + bo + aoff);                   \
        float ax = __uint_as_float(u.x << 16);                           \
        float ay = __uint_as_float(u.x & 0xffff0000u);                   \
        float az = __uint_as_float(u.y << 16);                           \
        float aw = __uint_as_float(u.y & 0xffff0000u);                   \
        float v0 = hr.x + ax, v1 = hr.y + ay;                            \
        float v2 = hr.z + az, v3 = hr.w + aw;                            \
        float ts = fmaf(fabsf(v3), at.w, fmaf(fabsf(v2), at.z,           \
                   fmaf(fabsf(v1), at.y, fabsf(v0) * at.x)));            \
        ts += __shfl_xor(ts, 1); ts += __shfl_xor(ts, 2);                \
        ts += __shfl_xor(ts, 4);                                         \
        float p = __builtin_amdgcn_exp2f(ts + arl + alv);                \
        LACC += p;                                                       \
        ACC.x = fmaf(p, ax, ACC.x); ACC.y = fmaf(p, ay, ACC.y);          \
        ACC.z = fmaf(p, az, ACC.z); ACC.w = fmaf(p, aw, ACC.w);          \
    }

    for (int cb = beg; cb < end; cb += 64) {
        int cnt = min(64, end - cb);
        int my = cb + lane;
        int ss = (my < end) ? srcp[my] : n;   // sentinel node n: al=-1e30 -> p=0
        int npair = (cnt + 1) >> 1;
        int idx = half;
        int j = 0;
        for (; j + 2 <= npair; j += 2) {
            EDGE(idx, acc0, l0)
            EDGE(idx + 2, acc1, l1)
            idx += 4;
        }
        if (j < npair) EDGE(idx, acc0, l0)
    }
#undef EDGE

    acc0.x += acc1.x; acc0.y += acc1.y; acc0.z += acc1.z; acc0.w += acc1.w;
    float l = l0 + l1;
    int partner = hl5 + 32;
    acc0.x += __shfl(acc0.x, partner, 64);
    acc0.y += __shfl(acc0.y, partner, 64);
    acc0.z += __shfl(acc0.z, partner, 64);
    acc0.w += __shfl(acc0.w, partner, 64);
    l      += __shfl(l, partner, 64);

    if (half == 0 && active) {
        float inv = 1.0f / (l + 1e-16f);
        size_t o = (size_t)node * 96 + c;
        float4 sk = *(const float4*)(SK + o);
        float4 bs = *(const float4*)(bias + c);
        float4 ov;
        ov.x = fmaf(acc0.x, inv, bs.x + sk.x);
        ov.y = fmaf(acc0.y, inv, bs.y + sk.y);
        ov.z = fmaf(acc0.z, inv, bs.z + sk.z);
        ov.w = fmaf(acc0.w, inv, bs.w + sk.w);
        if (do_relu) {
            ov.x = fmaxf(ov.x, 0.f); ov.y = fmaxf(ov.y, 0.f);
            ov.z = fmaxf(ov.z, 0.f); ov.w = fmaxf(ov.w, 0.f);
        }
        *(float4*)(out + o) = ov;
    }
}

extern "C" void kernel_launch(void* const* d_in, const int* in_sizes, int n_in,
                              void* d_out, int out_size, void* d_ws, size_t ws_size,
                              hipStream_t stream) {
    const float* x     = (const float*)d_in[0];
    const int*   ei    = (const int*)d_in[1];    // [2,E]: src = ei[0:E], dst = ei[E:2E]
    const float* W0    = (const float*)d_in[2];
    const float* Wl1   = (const float*)d_in[3];
    const float* bl1   = (const float*)d_in[4];
    const float* Wr1   = (const float*)d_in[5];
    const float* br1   = (const float*)d_in[6];
    const float* att1  = (const float*)d_in[7];
    const float* b1    = (const float*)d_in[8];
    const float* Wf    = (const float*)d_in[9];
    const float* bf    = (const float*)d_in[10];
    const float* Wl2   = (const float*)d_in[11];
    const float* bl2   = (const float*)d_in[12];
    const float* Wr2   = (const float*)d_in[13];
    const float* br2   = (const float*)d_in[14];
    const float* att2  = (const float*)d_in[15];
    const float* b2    = (const float*)d_in[16];
    const float* Wlast = (const float*)d_in[17];
    const float* blast = (const float*)d_in[18];

    const int* src = ei;
    const int* dst = ei + NE;

    size_t off = 0;
    auto carve = [&](size_t bytes) {
        void* p = (char*)d_ws + off;
        off += (bytes + 255) & ~(size_t)255;
        return p;
    };
    unsigned short* HLb = (unsigned short*)carve((size_t)(NN + 1) * 128 * 2);  // 256B rows: 96ch + 3 al + sentinel row
    unsigned short* HRb = (unsigned short*)carve((size_t)NN * 96 * 2);
    float* SK  = (float*)carve((size_t)NN * 96 * 4);
    float* H   = (float*)carve((size_t)NN * 96 * 4);   // h1; arena aliases this
    float* h0  = (float*)carve((size_t)NN * 16 * 4);
    int* rowptr  = (int*)carve((size_t)(NN + 1) * 4);
    int* srcp    = (int*)carve((size_t)(NE + 64) * 4);
    int* T       = (int*)carve((size_t)(NBKT + 8) * 4);     // per-bucket degree (atomic reservation)
    unsigned short* bhi2 = (unsigned short*)carve((size_t)18 * 3 * 64 * 8 * 2);
    unsigned short* blo2 = (unsigned short*)carve((size_t)18 * 3 * 64 * 8 * 2);
    int* arena = (int*)H;   // alias: bucket-major edge arena, dead before k_agg writes H
    (void)ws_size; (void)n_in; (void)in_sizes; (void)out_size;

    const int XF_BLOCKS = (NN + 63) / 64;          // 1563

    // CSR build v3: memset + 2 kernels
    hipMemsetAsync(T, 0, (size_t)NBKT * sizeof(int), stream);
    k_bscat<<<NBLK1, 512, 0, stream>>>(dst, src, T, arena);
    k_bsort<<<NBKT, 512, 0, stream>>>(T, arena, srcp, rowptr);

    // pack layer-2 weights into MFMA fragments + init sentinel row (tiny)
    k_prepw2<<<14, 256, 0, stream>>>(Wl2, Wr2, Wlast, bhi2, blo2, HLb);

    // dense pipeline, layer 1
    k_lin0<<<NN / 16, 256, 0, stream>>>(x, W0, h0, NN);
    k_xform1<<<XF_BLOCKS, dim3(96, 4), 0, stream>>>(h0, Wl1, bl1, Wr1, br1, Wf, bf, att1, HLb, HRb, SK, NN);
    k_agg<<<(NN + 3) / 4, 256, 0, stream>>>(rowptr, srcp, HLb, HRb, att1, b1, SK, H, NN, 1);

    // layer 2 transforms: MFMA split-precision GEMM (no LDS, reg-resident B, fused al)
    k_xform2m<<<XF_BLOCKS, 256, 0, stream>>>(H, bhi2, blo2, bl2, br2, blast, att2, HLb, HRb, SK);
    k_agg<<<(NN + 3) / 4, 256, 0, stream>>>(rowptr, srcp, HLb, HRb, att2, b2, SK, (float*)d_out, NN, 0);
}